// Round 4
// baseline (5749.466 us; speedup 1.0000x reference)
//
#include <hip/hip_runtime.h>

// FSRCNN fully fused, one 1024-thr block per image, 1 px/thread. Round 4:
//  - amdgpu_waves_per_eu(4,4): pin allocator to 4 waves/EU (the real LDS-bound
//    occupancy) -> VGPR cap 128, kills the round-3 spill (VGPR=64, 4.7GB scratch).
//  - Tail H chunks double-buffered in dead A/B regions: 1 barrier per chunk,
//    b6 FMAs of chunk k+1 overlap LDS writes of chunk k.
//  - All-fp32; all ds ops designed 2-way-or-less bank aliasing (free).
//  - Weights/biases from global, wave-uniform -> s_load on scalar pipe.

#define TB 1024
#define X_OFF 0        // 3*36*36 = 3888 floats (padded input, pad=2)
#define A_OFF 3888     // 12*34*34 = 13872 floats (padded, pad=1)
#define B_OFF 17760    // 12*34*34
#define LDS_FLOATS 31632
#define LDS_BYTES (LDS_FLOATS * 4)   // 126528 B
// H chunk buffers: 8 ch x [36][37] f32 = 10656 floats each.
// HC0 overlays A (dead after b3-read), HC1 overlays B (dead after b4-read).
#define HC0 A_OFF
#define HC1 B_OFF
#define HCH   1332     // 36*37 per channel
#define HSTR  37

__global__ void __launch_bounds__(TB)
__attribute__((amdgpu_waves_per_eu(4, 4)))
fsrcnn_fused(const float* __restrict__ x,
             const float* __restrict__ head_w, const float* __restrict__ head_b, const float* __restrict__ head_a,
             const float* __restrict__ b0_w, const float* __restrict__ b0_b, const float* __restrict__ b0_a,
             const float* __restrict__ b1_w, const float* __restrict__ b1_b,
             const float* __restrict__ b2_w, const float* __restrict__ b2_b,
             const float* __restrict__ b3_w, const float* __restrict__ b3_b,
             const float* __restrict__ b4_w, const float* __restrict__ b4_b,
             const float* __restrict__ b5_a,
             const float* __restrict__ b6_w, const float* __restrict__ b6_b, const float* __restrict__ b6_a,
             const float* __restrict__ tail_w, const float* __restrict__ tail_b,
             float* __restrict__ out)
{
    extern __shared__ float lds[];
    const int tid = threadIdx.x;
    const int img = blockIdx.x;
    const int y   = tid >> 5;      // 0..31
    const int xp  = tid & 31;      // 0..31

    // ---------------- stage padded x (3x36x36), zero A+B ----------------
    {
        const float* xg = x + img * 3072;
        for (int i = tid; i < 3888; i += TB) {
            const int c = i / 1296;
            const int rem = i - c * 1296;
            const int r = rem / 36;
            const int cl = rem - r * 36;
            const int iy = r - 2, ix = cl - 2;
            float v = 0.f;
            if ((unsigned)iy < 32u && (unsigned)ix < 32u)
                v = xg[(c << 10) + (iy << 5) + ix];
            lds[X_OFF + i] = v;
        }
        float4* ab = reinterpret_cast<float4*>(&lds[A_OFF]);
        const float4 z4 = make_float4(0.f, 0.f, 0.f, 0.f);
        for (int i = tid; i < 6936; i += TB) ab[i] = z4;   // zero A and B
    }
    __syncthreads();

    // ---------------- head 5x5 3->56 + prelu + b0 1x1 56->12 + prelu -> A ----------------
    float accS[12];
    #pragma unroll
    for (int s = 0; s < 12; s++) accS[s] = b0_b[s];
    for (int d0 = 0; d0 < 56; d0 += 8) {
        float ah[8];
        #pragma unroll
        for (int dd = 0; dd < 8; dd++) ah[dd] = head_b[d0 + dd];
        #pragma unroll
        for (int ci = 0; ci < 3; ci++) {
            #pragma unroll
            for (int ky = 0; ky < 5; ky++) {
                const float* xr = &lds[X_OFF + ci * 1296 + (y + ky) * 36 + xp];
                float xv[5];
                #pragma unroll
                for (int t = 0; t < 5; t++) xv[t] = xr[t];
                #pragma unroll
                for (int dd = 0; dd < 8; dd++) {
                    const float* wr = &head_w[((d0 + dd) * 3 + ci) * 25 + ky * 5];
                    #pragma unroll
                    for (int kx = 0; kx < 5; kx++)
                        ah[dd] = fmaf(xv[kx], wr[kx], ah[dd]);   // wr uniform -> s_load
                }
            }
        }
        #pragma unroll
        for (int dd = 0; dd < 8; dd++) {
            const float al = head_a[d0 + dd];
            float v = ah[dd];
            v = (v >= 0.f) ? v : al * v;
            #pragma unroll
            for (int s = 0; s < 12; s++)
                accS[s] = fmaf(b0_w[s * 56 + d0 + dd], v, accS[s]);
        }
    }
    #pragma unroll
    for (int s = 0; s < 12; s++) {
        const float al = b0_a[s];
        float v = accS[s];
        v = (v >= 0.f) ? v : al * v;
        lds[A_OFF + s * 1156 + (y + 1) * 34 + xp + 1] = v;
    }
    __syncthreads();

    // ---------------- b1..b3: 3x3 12->12 pad1, LDS->LDS ----------------
    auto conv3 = [&](int pofs, int qofs, const float* __restrict__ w, const float* __restrict__ bias) {
        float acc[12];
        #pragma unroll
        for (int c = 0; c < 12; c++) acc[c] = bias[c];
        for (int e = 0; e < 12; e++) {
            #pragma unroll
            for (int ky = 0; ky < 3; ky++) {
                const float* pr = &lds[pofs + e * 1156 + (y + ky) * 34 + xp];
                float xv[3];
                xv[0] = pr[0]; xv[1] = pr[1]; xv[2] = pr[2];
                #pragma unroll
                for (int c = 0; c < 12; c++) {
                    const float* wr = &w[(c * 12 + e) * 9 + ky * 3];
                    #pragma unroll
                    for (int kx = 0; kx < 3; kx++)
                        acc[c] = fmaf(xv[kx], wr[kx], acc[c]);
                }
            }
        }
        #pragma unroll
        for (int c = 0; c < 12; c++)
            lds[qofs + c * 1156 + (y + 1) * 34 + xp + 1] = acc[c];
        __syncthreads();
    };
    conv3(A_OFF, B_OFF, b1_w, b1_b);
    conv3(B_OFF, A_OFF, b2_w, b2_b);
    conv3(A_OFF, B_OFF, b3_w, b3_b);

    // ---------------- b4: 3x3 + prelu(b5_a) -> registers g ----------------
    float g[12];
    #pragma unroll
    for (int c = 0; c < 12; c++) g[c] = b4_b[c];
    for (int e = 0; e < 12; e++) {
        #pragma unroll
        for (int ky = 0; ky < 3; ky++) {
            const float* pr = &lds[B_OFF + e * 1156 + (y + ky) * 34 + xp];
            float xv[3];
            xv[0] = pr[0]; xv[1] = pr[1]; xv[2] = pr[2];
            #pragma unroll
            for (int c = 0; c < 12; c++) {
                const float* wr = &b4_w[(c * 12 + e) * 9 + ky * 3];
                #pragma unroll
                for (int kx = 0; kx < 3; kx++)
                    g[c] = fmaf(xv[kx], wr[kx], g[c]);
            }
        }
    }
    #pragma unroll
    for (int c = 0; c < 12; c++) {
        const float al = b5_a[c];
        const float v = g[c];
        g[c] = (v >= 0.f) ? v : al * v;
    }
    __syncthreads();   // all reads of A and B done -> both regions reusable

    // ---------------- zero frames of both H chunk buffers ----------------
    // frame = rows {0,1,34,35} all 37 cols + rows 2..33 cols {0,1,34,35,36}
    for (int i = tid; i < 616; i += TB) {
        const int buf = (i < 308) ? HC0 : HC1;
        int idx = (i < 308) ? i : i - 308;
        int row, col;
        if (idx < 148) {
            const int q = idx / 37;
            row = (q < 2) ? q : 32 + q;
            col = idx - q * 37;
        } else {
            const int j = idx - 148;
            const int r5 = j % 5;
            row = 2 + j / 5;
            col = (r5 < 2) ? r5 : 32 + r5;   // 0,1,34,35,36
        }
        #pragma unroll
        for (int dd = 0; dd < 8; dd++)
            lds[buf + dd * HCH + row * HSTR + col] = 0.f;
    }

    // b6 (1x1 12->56 + prelu) for an 8-channel chunk -> LDS buffer
    auto stage_chunk = [&](int d0, int buf) {
        #pragma unroll
        for (int dd = 0; dd < 8; dd++) {
            const int d = d0 + dd;
            float v = b6_b[d];
            #pragma unroll
            for (int s = 0; s < 12; s++)
                v = fmaf(b6_w[d * 12 + s], g[s], v);
            const float al = b6_a[d];
            v = (v >= 0.f) ? v : al * v;
            lds[buf + dd * HCH + (y + 2) * HSTR + xp + 2] = v;
        }
    };

    // ---------------- tail: 9x9 stride-2 convT, chunked + double-buffered ----------------
    float acc[3][4];   // [c][ry*2+rx] -> out (2y+ry, 2xp+rx)
    #pragma unroll
    for (int c = 0; c < 3; c++) {
        const float tb = tail_b[c];
        #pragma unroll
        for (int q = 0; q < 4; q++) acc[c][q] = tb;
    }

    stage_chunk(0, HC0);           // frame-zero (disjoint) + chunk-0 interior
    __syncthreads();

    for (int k = 0; k < 7; k++) {
        const int cur = (k & 1) ? HC1 : HC0;
        if (k < 6) stage_chunk((k + 1) * 8, (k & 1) ? HC0 : HC1);
        const int d0 = k * 8;
        #pragma unroll
        for (int dd = 0; dd < 8; dd++) {
            const float* hb = &lds[cur + dd * HCH];
            const float* wb = &tail_w[(d0 + dd) * 243];   // [c][ky][kx], c stride 81
            #pragma unroll
            for (int j = 0; j < 5; j++) {                 // padded row y+j, m = 4-j
                const float* pr = hb + (y + j) * HSTR + xp;
                float xv[5];
                #pragma unroll
                for (int t = 0; t < 5; t++) xv[t] = pr[t];
                {   // ry = 0, ky = 8-2j
                    const int kyo = (8 - 2 * j) * 9;
                    #pragma unroll
                    for (int kx = 0; kx < 9; kx++) {
                        const int n = kx >> 1, rx = kx & 1;
                        #pragma unroll
                        for (int c = 0; c < 3; c++)
                            acc[c][rx] = fmaf(xv[4 - n], wb[c * 81 + kyo + kx], acc[c][rx]);
                    }
                }
                if (j >= 1) {   // ry = 1, ky = 9-2j
                    const int kyo = (9 - 2 * j) * 9;
                    #pragma unroll
                    for (int kx = 0; kx < 9; kx++) {
                        const int n = kx >> 1, rx = kx & 1;
                        #pragma unroll
                        for (int c = 0; c < 3; c++)
                            acc[c][2 + rx] = fmaf(xv[4 - n], wb[c * 81 + kyo + kx], acc[c][2 + rx]);
                    }
                }
            }
        }
        __syncthreads();
    }

    // ---------------- store 2x2 output block per thread ----------------
    float* op = out + (img * 3) * 4096 + (2 * y) * 64 + 2 * xp;
    #pragma unroll
    for (int c = 0; c < 3; c++) {
        *reinterpret_cast<float2*>(op + c * 4096)      = make_float2(acc[c][0], acc[c][1]);
        *reinterpret_cast<float2*>(op + c * 4096 + 64) = make_float2(acc[c][2], acc[c][3]);
    }
}

extern "C" void kernel_launch(void* const* d_in, const int* in_sizes, int n_in,
                              void* d_out, int out_size, void* d_ws, size_t ws_size,
                              hipStream_t stream) {
    (void)in_sizes; (void)n_in; (void)d_ws; (void)ws_size; (void)out_size;
    const float* x      = (const float*)d_in[0];
    const float* head_w = (const float*)d_in[1];
    const float* head_b = (const float*)d_in[2];
    const float* head_a = (const float*)d_in[3];
    const float* b0_w   = (const float*)d_in[4];
    const float* b0_b   = (const float*)d_in[5];
    const float* b0_a   = (const float*)d_in[6];
    const float* b1_w   = (const float*)d_in[7];
    const float* b1_b   = (const float*)d_in[8];
    const float* b2_w   = (const float*)d_in[9];
    const float* b2_b   = (const float*)d_in[10];
    const float* b3_w   = (const float*)d_in[11];
    const float* b3_b   = (const float*)d_in[12];
    const float* b4_w   = (const float*)d_in[13];
    const float* b4_b   = (const float*)d_in[14];
    const float* b5_a   = (const float*)d_in[15];
    const float* b6_w   = (const float*)d_in[16];
    const float* b6_b   = (const float*)d_in[17];
    const float* b6_a   = (const float*)d_in[18];
    const float* tail_w = (const float*)d_in[19];
    const float* tail_b = (const float*)d_in[20];
    float* out = (float*)d_out;

    hipFuncSetAttribute(reinterpret_cast<const void*>(fsrcnn_fused),
                        hipFuncAttributeMaxDynamicSharedMemorySize, LDS_BYTES);
    fsrcnn_fused<<<1024, TB, LDS_BYTES, stream>>>(
        x, head_w, head_b, head_a, b0_w, b0_b, b0_a,
        b1_w, b1_b, b2_w, b2_b, b3_w, b3_b, b4_w, b4_b, b5_a,
        b6_w, b6_b, b6_a, tail_w, tail_b, out);
}

// Round 5
// 2384.049 us; speedup vs baseline: 2.4116x; 2.4116x over previous
//
#include <hip/hip_runtime.h>
#include <hip/hip_fp16.h>

// FSRCNN fully fused, one 512-thr block per image, 2 px/thread. Round 5:
//  - __launch_bounds__(512,2): the ONLY empirically non-spilling config
//    (R2: VGPR=128). Second launch_bounds arg acts CUDA-style (min blocks/CU)
//    on this toolchain: (1024,4)/waves_per_eu both gave VGPR=64 + 4.7GB spill.
//  - LDS cut to 74304 B/block -> 2 blocks/CU = 16 waves/CU; cross-block
//    overlap hides barrier drains.
//  - Conv-chain ping/pong buffers fp16 [12][34][36] (even-aligned half2 IO);
//    X fp32; tail H chunks fp32 4ch x [36][38] double-buffered over dead X+A.
//  - Weights/biases wave-uniform from global -> s_load on scalar pipe.

#define TB 512
// float-index layout
#define XF   0                 // X fp32 [3][36][36] = 3888 floats (bytes 0..15551)
// half-index layout (overlays floats from byte 15552)
#define AH   7776              // A fp16 [12][34][36] = 14688 halfs (bytes 15552..44927)
#define BH   22464             // B fp16 [12][34][36]            (bytes 44928..74303)
#define HCST 1224              // 34*36 halfs per channel
// tail chunk buffers (fp32), overlay X+A (dead after b3-read)
#define CH0F 0                 // 4ch x [36][38] = 5472 floats (bytes 0..21887)
#define CH1F 5472              //                               (bytes 21888..43775)
#define CCST 1368              // 36*38 floats per channel
#define LDS_BYTES 74304

__global__ void __launch_bounds__(TB, 2)
fsrcnn_fused(const float* __restrict__ x,
             const float* __restrict__ head_w, const float* __restrict__ head_b, const float* __restrict__ head_a,
             const float* __restrict__ b0_w, const float* __restrict__ b0_b, const float* __restrict__ b0_a,
             const float* __restrict__ b1_w, const float* __restrict__ b1_b,
             const float* __restrict__ b2_w, const float* __restrict__ b2_b,
             const float* __restrict__ b3_w, const float* __restrict__ b3_b,
             const float* __restrict__ b4_w, const float* __restrict__ b4_b,
             const float* __restrict__ b5_a,
             const float* __restrict__ b6_w, const float* __restrict__ b6_b, const float* __restrict__ b6_a,
             const float* __restrict__ tail_w, const float* __restrict__ tail_b,
             float* __restrict__ out)
{
    extern __shared__ float lds[];
    __half* hp = reinterpret_cast<__half*>(lds);
    const int tid = threadIdx.x;
    const int img = blockIdx.x;
    const int y  = tid >> 4;           // 0..31 interior row
    const int xi = (tid & 15) << 1;    // 0..30 interior col base (even), 2 px/thread

    // ---------------- stage padded x (3x36x36 fp32), zero A+B (fp16) ----------------
    {
        const float* xg = x + img * 3072;
        for (int i = tid; i < 3888; i += TB) {
            const int c = i / 1296;
            const int rem = i - c * 1296;
            const int r = rem / 36;
            const int cl = rem - r * 36;
            const int iy = r - 2, ix = cl - 2;
            float v = 0.f;
            if ((unsigned)iy < 32u && (unsigned)ix < 32u)
                v = xg[(c << 10) + (iy << 5) + ix];
            lds[XF + i] = v;
        }
        float4* ab = reinterpret_cast<float4*>(&lds[3888]);   // bytes 15552..74303
        const float4 z4 = make_float4(0.f, 0.f, 0.f, 0.f);
        for (int i = tid; i < 3672; i += TB) ab[i] = z4;
    }
    __syncthreads();

    // ---------------- head 5x5 3->56 + prelu + b0 1x1 56->12 + prelu -> A(fp16) ----------------
    float accS[12][2];
    #pragma unroll
    for (int s = 0; s < 12; s++) { const float bb = b0_b[s]; accS[s][0] = bb; accS[s][1] = bb; }
    for (int d0 = 0; d0 < 56; d0 += 4) {
        float ah[4][2];
        #pragma unroll
        for (int dd = 0; dd < 4; dd++) { const float hb = head_b[d0 + dd]; ah[dd][0] = hb; ah[dd][1] = hb; }
        #pragma unroll
        for (int ci = 0; ci < 3; ci++) {
            #pragma unroll
            for (int ky = 0; ky < 5; ky++) {
                const float* xr = &lds[XF + ci * 1296 + (y + ky) * 36 + xi];
                float xv[6];
                *reinterpret_cast<float2*>(&xv[0]) = *reinterpret_cast<const float2*>(xr);
                *reinterpret_cast<float2*>(&xv[2]) = *reinterpret_cast<const float2*>(xr + 2);
                *reinterpret_cast<float2*>(&xv[4]) = *reinterpret_cast<const float2*>(xr + 4);
                #pragma unroll
                for (int dd = 0; dd < 4; dd++) {
                    const float* wr = &head_w[((d0 + dd) * 3 + ci) * 25 + ky * 5];
                    #pragma unroll
                    for (int kx = 0; kx < 5; kx++) {
                        const float w = wr[kx];                 // uniform -> s_load
                        ah[dd][0] = fmaf(xv[kx],     w, ah[dd][0]);
                        ah[dd][1] = fmaf(xv[kx + 1], w, ah[dd][1]);
                    }
                }
            }
        }
        #pragma unroll
        for (int dd = 0; dd < 4; dd++) {
            const float al = head_a[d0 + dd];
            float v0 = ah[dd][0]; v0 = (v0 >= 0.f) ? v0 : al * v0;
            float v1 = ah[dd][1]; v1 = (v1 >= 0.f) ? v1 : al * v1;
            #pragma unroll
            for (int s = 0; s < 12; s++) {
                const float w = b0_w[s * 56 + d0 + dd];
                accS[s][0] = fmaf(w, v0, accS[s][0]);
                accS[s][1] = fmaf(w, v1, accS[s][1]);
            }
        }
    }
    #pragma unroll
    for (int s = 0; s < 12; s++) {
        const float al = b0_a[s];
        float v0 = accS[s][0]; v0 = (v0 >= 0.f) ? v0 : al * v0;
        float v1 = accS[s][1]; v1 = (v1 >= 0.f) ? v1 : al * v1;
        *reinterpret_cast<__half2*>(hp + AH + s * HCST + (y + 1) * 36 + xi + 2) =
            __floats2half2_rn(v0, v1);
    }
    __syncthreads();

    // ---------------- b1..b3: 3x3 12->12 pad1, fp16 LDS->LDS ----------------
    auto conv3 = [&](int inB, int outB, const float* __restrict__ w, const float* __restrict__ bias) {
        float acc[12][2];
        #pragma unroll
        for (int c = 0; c < 12; c++) { const float bb = bias[c]; acc[c][0] = bb; acc[c][1] = bb; }
        for (int e = 0; e < 12; e++) {
            #pragma unroll
            for (int ky = 0; ky < 3; ky++) {
                const __half2* pr = reinterpret_cast<const __half2*>(hp + inB + e * HCST + (y + ky) * 36 + xi);
                float xv[6];
                float2 f;
                f = __half22float2(pr[0]); xv[0] = f.x; xv[1] = f.y;
                f = __half22float2(pr[1]); xv[2] = f.x; xv[3] = f.y;
                f = __half22float2(pr[2]); xv[4] = f.x; xv[5] = f.y;
                #pragma unroll
                for (int c = 0; c < 12; c++) {
                    const float* wr = &w[(c * 12 + e) * 9 + ky * 3];
                    #pragma unroll
                    for (int kx = 0; kx < 3; kx++) {
                        const float wv = wr[kx];
                        acc[c][0] = fmaf(xv[1 + kx], wv, acc[c][0]);
                        acc[c][1] = fmaf(xv[2 + kx], wv, acc[c][1]);
                    }
                }
            }
        }
        #pragma unroll
        for (int c = 0; c < 12; c++)
            *reinterpret_cast<__half2*>(hp + outB + c * HCST + (y + 1) * 36 + xi + 2) =
                __floats2half2_rn(acc[c][0], acc[c][1]);
        __syncthreads();
    };
    conv3(AH, BH, b1_w, b1_b);
    conv3(BH, AH, b2_w, b2_b);
    conv3(AH, BH, b3_w, b3_b);

    // ---------------- b4: 3x3 + prelu(b5_a) -> registers g (fp32) ----------------
    float g[12][2];
    #pragma unroll
    for (int c = 0; c < 12; c++) { const float bb = b4_b[c]; g[c][0] = bb; g[c][1] = bb; }
    for (int e = 0; e < 12; e++) {
        #pragma unroll
        for (int ky = 0; ky < 3; ky++) {
            const __half2* pr = reinterpret_cast<const __half2*>(hp + BH + e * HCST + (y + ky) * 36 + xi);
            float xv[6];
            float2 f;
            f = __half22float2(pr[0]); xv[0] = f.x; xv[1] = f.y;
            f = __half22float2(pr[1]); xv[2] = f.x; xv[3] = f.y;
            f = __half22float2(pr[2]); xv[4] = f.x; xv[5] = f.y;
            #pragma unroll
            for (int c = 0; c < 12; c++) {
                const float* wr = &b4_w[(c * 12 + e) * 9 + ky * 3];
                #pragma unroll
                for (int kx = 0; kx < 3; kx++) {
                    const float wv = wr[kx];
                    g[c][0] = fmaf(xv[1 + kx], wv, g[c][0]);
                    g[c][1] = fmaf(xv[2 + kx], wv, g[c][1]);
                }
            }
        }
    }
    #pragma unroll
    for (int c = 0; c < 12; c++) {
        const float al = b5_a[c];
        float v0 = g[c][0]; g[c][0] = (v0 >= 0.f) ? v0 : al * v0;
        float v1 = g[c][1]; g[c][1] = (v1 >= 0.f) ? v1 : al * v1;
    }

    // ---------------- zero tail chunk buffers (overlay X+A; A dead after b3) ----------------
    {
        float4* ch = reinterpret_cast<float4*>(&lds[0]);
        const float4 z4 = make_float4(0.f, 0.f, 0.f, 0.f);
        for (int i = tid; i < 2736; i += TB) ch[i] = z4;   // CH0+CH1 = 10944 floats
    }
    __syncthreads();

    // b6 (1x1 12->56 + prelu) for a 4-channel chunk -> fp32 LDS buffer
    auto stage4 = [&](int d0, int baseF) {
        #pragma unroll
        for (int dd = 0; dd < 4; dd++) {
            const int d = d0 + dd;
            float v0 = b6_b[d], v1 = v0;
            #pragma unroll
            for (int s = 0; s < 12; s++) {
                const float w = b6_w[d * 12 + s];
                v0 = fmaf(w, g[s][0], v0);
                v1 = fmaf(w, g[s][1], v1);
            }
            const float al = b6_a[d];
            v0 = (v0 >= 0.f) ? v0 : al * v0;
            v1 = (v1 >= 0.f) ? v1 : al * v1;
            *reinterpret_cast<float2*>(&lds[baseF + dd * CCST + (y + 2) * 38 + xi + 2]) =
                make_float2(v0, v1);
        }
    };

    // ---------------- tail: 9x9 stride-2 convT 56->3, 14 chunks double-buffered ----------------
    float acc[3][2][4];   // [c][ry][q] -> out(2y+ry, 2xi+q)
    #pragma unroll
    for (int c = 0; c < 3; c++) {
        const float tb = tail_b[c];
        #pragma unroll
        for (int r = 0; r < 2; r++)
            #pragma unroll
            for (int q = 0; q < 4; q++) acc[c][r][q] = tb;
    }

    stage4(0, CH0F);
    __syncthreads();

    for (int k = 0; k < 14; k++) {
        const int cur = (k & 1) ? CH1F : CH0F;
        if (k < 13) stage4((k + 1) * 4, (k & 1) ? CH0F : CH1F);
        const int d0 = k * 4;
        #pragma unroll
        for (int dd = 0; dd < 4; dd++) {
            const float* hb = &lds[cur + dd * CCST];
            const float* wb = &tail_w[(d0 + dd) * 243];   // [c][ky][kx], c stride 81
            #pragma unroll
            for (int j = 0; j < 5; j++) {                 // buffer row y+j; m = 4-j
                const float* pr = hb + (y + j) * 38 + xi;
                float xv[6];
                *reinterpret_cast<float2*>(&xv[0]) = *reinterpret_cast<const float2*>(pr);
                *reinterpret_cast<float2*>(&xv[2]) = *reinterpret_cast<const float2*>(pr + 2);
                *reinterpret_cast<float2*>(&xv[4]) = *reinterpret_cast<const float2*>(pr + 4);
                {   // ry = 0, ky = 8-2j
                    const int kyo = (8 - 2 * j) * 9;
                    #pragma unroll
                    for (int kx = 0; kx < 9; kx++) {
                        const int n = kx >> 1, rx = kx & 1;
                        #pragma unroll
                        for (int c = 0; c < 3; c++) {
                            const float w = wb[c * 81 + kyo + kx];
                            acc[c][0][rx]     = fmaf(xv[4 - n], w, acc[c][0][rx]);
                            acc[c][0][2 + rx] = fmaf(xv[5 - n], w, acc[c][0][2 + rx]);
                        }
                    }
                }
                if (j >= 1) {   // ry = 1, ky = 9-2j
                    const int kyo = (9 - 2 * j) * 9;
                    #pragma unroll
                    for (int kx = 0; kx < 9; kx++) {
                        const int n = kx >> 1, rx = kx & 1;
                        #pragma unroll
                        for (int c = 0; c < 3; c++) {
                            const float w = wb[c * 81 + kyo + kx];
                            acc[c][1][rx]     = fmaf(xv[4 - n], w, acc[c][1][rx]);
                            acc[c][1][2 + rx] = fmaf(xv[5 - n], w, acc[c][1][2 + rx]);
                        }
                    }
                }
            }
        }
        __syncthreads();
    }

    // ---------------- store 2 rows x 4 cols per thread, per channel ----------------
    float* op = out + (img * 3) * 4096 + (2 * y) * 64 + 2 * xi;
    #pragma unroll
    for (int c = 0; c < 3; c++) {
        *reinterpret_cast<float4*>(op + c * 4096)      = make_float4(acc[c][0][0], acc[c][0][1], acc[c][0][2], acc[c][0][3]);
        *reinterpret_cast<float4*>(op + c * 4096 + 64) = make_float4(acc[c][1][0], acc[c][1][1], acc[c][1][2], acc[c][1][3]);
    }
}

extern "C" void kernel_launch(void* const* d_in, const int* in_sizes, int n_in,
                              void* d_out, int out_size, void* d_ws, size_t ws_size,
                              hipStream_t stream) {
    (void)in_sizes; (void)n_in; (void)d_ws; (void)ws_size; (void)out_size;
    const float* x      = (const float*)d_in[0];
    const float* head_w = (const float*)d_in[1];
    const float* head_b = (const float*)d_in[2];
    const float* head_a = (const float*)d_in[3];
    const float* b0_w   = (const float*)d_in[4];
    const float* b0_b   = (const float*)d_in[5];
    const float* b0_a   = (const float*)d_in[6];
    const float* b1_w   = (const float*)d_in[7];
    const float* b1_b   = (const float*)d_in[8];
    const float* b2_w   = (const float*)d_in[9];
    const float* b2_b   = (const float*)d_in[10];
    const float* b3_w   = (const float*)d_in[11];
    const float* b3_b   = (const float*)d_in[12];
    const float* b4_w   = (const float*)d_in[13];
    const float* b4_b   = (const float*)d_in[14];
    const float* b5_a   = (const float*)d_in[15];
    const float* b6_w   = (const float*)d_in[16];
    const float* b6_b   = (const float*)d_in[17];
    const float* b6_a   = (const float*)d_in[18];
    const float* tail_w = (const float*)d_in[19];
    const float* tail_b = (const float*)d_in[20];
    float* out = (float*)d_out;

    hipFuncSetAttribute(reinterpret_cast<const void*>(fsrcnn_fused),
                        hipFuncAttributeMaxDynamicSharedMemorySize, LDS_BYTES);
    fsrcnn_fused<<<1024, TB, LDS_BYTES, stream>>>(
        x, head_w, head_b, head_a, b0_w, b0_b, b0_a,
        b1_w, b1_b, b2_w, b2_b, b3_w, b3_b, b4_w, b4_b, b5_a,
        b6_w, b6_b, b6_a, tail_w, tail_b, out);
}